// Round 11
// baseline (192.536 us; speedup 1.0000x reference)
//
#include <hip/hip_runtime.h>

// GCNPredictor: 3-layer GCN (sum-aggregation) + sum-pool + MLP head.
// Round 11: R9 base (best: 167us) + explicit A/B ping-pong software pipeline
// in the gather (load group g+1 while doing math on group g; zero copies),
// masked single-group tail (no serial remainder), __launch_bounds__(256,2)
// so the register allocator can hold both 64-VGPR data groups live.

constexpr int NUM_GRAPHS = 2048;

typedef _Float16 f16x8 __attribute__((ext_vector_type(8)));
typedef float f32x4 __attribute__((ext_vector_type(4)));

// ---------------- h0 = x @ W_emb  ([N,35] @ [35,8]) ----------------
__global__ __launch_bounds__(256) void k_embed(const float* __restrict__ x,
                                               const float* __restrict__ Wemb,
                                               float* __restrict__ h0, int N) {
  __shared__ float sx[32 * 35];
  __shared__ float sw[35 * 8];
  int n0 = blockIdx.x * 32;
  int cnt = min(32, N - n0);
  int nf = cnt * 35;
  for (int i = threadIdx.x; i < nf; i += 256) sx[i] = x[(size_t)n0 * 35 + i];
  for (int i = threadIdx.x; i < 35 * 8; i += 256) sw[i] = Wemb[i];
  __syncthreads();
  int nl = threadIdx.x >> 3;
  int c = threadIdx.x & 7;
  if (nl < cnt) {
    float acc = 0.f;
#pragma unroll
    for (int k = 0; k < 35; ++k) acc = fmaf(sx[nl * 35 + k], sw[k * 8 + c], acc);
    h0[(size_t)(n0 + nl) * 8 + c] = acc;
  }
}

// ---------------- CSR build: counts -> exclusive scan -> fill ----------------
__global__ __launch_bounds__(256) void k_hist(const int* __restrict__ dst,
                                              int* counts, int E) {
  int e = blockIdx.x * 256 + threadIdx.x;
  if (e < E) atomicAdd(&counts[dst[e]], 1);
}

__global__ __launch_bounds__(256) void k_scan1(const int* __restrict__ counts,
                                               int* __restrict__ offs,
                                               int* __restrict__ partials, int N) {
  __shared__ int s[256];
  int i = blockIdx.x * 256 + threadIdx.x;
  int v = (i < N) ? counts[i] : 0;
  s[threadIdx.x] = v;
  __syncthreads();
#pragma unroll
  for (int d = 1; d < 256; d <<= 1) {
    int t = (threadIdx.x >= d) ? s[threadIdx.x - d] : 0;
    __syncthreads();
    s[threadIdx.x] += t;
    __syncthreads();
  }
  if (i < N) offs[i] = s[threadIdx.x] - v;  // exclusive
  if (threadIdx.x == 255) partials[blockIdx.x] = s[255];
}

__global__ __launch_bounds__(512) void k_scan2(int* partials, int nb) {
  __shared__ int s[512];
  int t = threadIdx.x;
  int orig = (t < nb) ? partials[t] : 0;
  s[t] = orig;
  __syncthreads();
#pragma unroll
  for (int d = 1; d < 512; d <<= 1) {
    int v = (t >= d) ? s[t - d] : 0;
    __syncthreads();
    s[t] += v;
    __syncthreads();
  }
  if (t < nb) partials[t] = s[t] - orig;  // exclusive block offsets
}

__global__ __launch_bounds__(256) void k_scan3(int* __restrict__ offs,
                                               const int* __restrict__ partials,
                                               int* __restrict__ cursor, int N) {
  int i = blockIdx.x * 256 + threadIdx.x;
  if (i < N) {
    int v = offs[i] + partials[blockIdx.x];
    offs[i] = v;
    cursor[i] = v;
  }
}

__global__ __launch_bounds__(256) void k_fill(const int* __restrict__ src,
                                              const int* __restrict__ dst,
                                              int* cursor, int* __restrict__ csr,
                                              int E) {
  int e = blockIdx.x * 256 + threadIdx.x;
  if (e < E) {
    int slot = atomicAdd(&cursor[dst[e]], 1);
    csr[slot] = src[e];
  }
}

// ---- W transpose + fp16 cast: WT[n][k] = W[k][n], 128x128, two matrices ----
__global__ __launch_bounds__(128) void k_prepw(const float* __restrict__ W1,
                                               const float* __restrict__ W2,
                                               _Float16* __restrict__ WT1,
                                               _Float16* __restrict__ WT2) {
  int n = blockIdx.x & 127;
  const float* W = (blockIdx.x < 128) ? W1 : W2;
  _Float16* WT = (blockIdx.x < 128) ? WT1 : WT2;
  int k = threadIdx.x;
  WT[(size_t)n * 128 + k] = (_Float16)W[(size_t)k * 128 + n];
}

// -------- layer 0 fused: agg8 = gather(h0); out = relu(agg8 @ W_g0), fp16 out
__global__ __launch_bounds__(256) void k_layer0(const float* __restrict__ h0,
                                                const int* __restrict__ csr,
                                                const int* __restrict__ offs,
                                                const int* __restrict__ cnts,
                                                const float* __restrict__ W,
                                                _Float16* __restrict__ out, int N) {
  __shared__ float sagg[32 * 9];  // stride 9: conflict-free
  __shared__ float sw[8 * 128];
  for (int i = threadIdx.x; i < 1024; i += 256) sw[i] = W[i];
  int n0 = blockIdx.x * 32;
  {
    int i = threadIdx.x >> 3;
    int c = threadIdx.x & 7;
    int n = n0 + i;
    float acc = 0.f;
    if (n < N) {
      int s = offs[n], cc = cnts[n];
      for (int e = 0; e < cc; ++e) acc += h0[(size_t)csr[s + e] * 8 + c];
    }
    sagg[i * 9 + c] = acc;
  }
  __syncthreads();
  int i2 = threadIdx.x >> 3;
  int j0 = (threadIdx.x & 7) * 16;
  int n2 = n0 + i2;
  if (n2 >= N) return;
  float a[8];
#pragma unroll
  for (int k = 0; k < 8; ++k) a[k] = sagg[i2 * 9 + k];
  float og[16];
#pragma unroll
  for (int j = 0; j < 16; ++j) og[j] = 0.f;
#pragma unroll
  for (int k = 0; k < 8; ++k)
#pragma unroll
    for (int j = 0; j < 16; ++j) og[j] = fmaf(a[k], sw[k * 128 + j0 + j], og[j]);
  size_t base = (size_t)n2 * 128 + j0;
  f16x8 o0, o1;
#pragma unroll
  for (int j = 0; j < 8; ++j) {
    o0[j] = (_Float16)fmaxf(og[j], 0.f);
    o1[j] = (_Float16)fmaxf(og[8 + j], 0.f);
  }
  *reinterpret_cast<f16x8*>(out + base) = o0;
  *reinterpret_cast<f16x8*>(out + base + 8) = o1;
}

// accumulate 8 halves into two float4 accumulators
__device__ __forceinline__ void acc_f16x8(float4& a0, float4& a1, const f16x8 h) {
  a0.x += (float)h[0]; a0.y += (float)h[1]; a0.z += (float)h[2]; a0.w += (float)h[3];
  a1.x += (float)h[4]; a1.y += (float)h[5]; a1.z += (float)h[6]; a1.w += (float)h[7];
}
// masked accumulate: acc += s * h
__device__ __forceinline__ void acc_fma8(float4& a0, float4& a1, const f16x8 h,
                                         float s) {
  a0.x = fmaf(s, (float)h[0], a0.x); a0.y = fmaf(s, (float)h[1], a0.y);
  a0.z = fmaf(s, (float)h[2], a0.z); a0.w = fmaf(s, (float)h[3], a0.w);
  a1.x = fmaf(s, (float)h[4], a1.x); a1.y = fmaf(s, (float)h[5], a1.y);
  a1.z = fmaf(s, (float)h[6], a1.z); a1.w = fmaf(s, (float)h[7], a1.w);
}

// load one 4-edge group (16 x f16x8) into BUF
#define LOADG(BUF, G)                                                         \
  {                                                                           \
    int b_ = sb + ((G) << 2);                                                 \
    int i0_ = sidx[b_], i1_ = sidx[b_ + 1];                                   \
    int i2_ = sidx[b_ + 2], i3_ = sidx[b_ + 3];                               \
    const f16x8* r0_ = reinterpret_cast<const f16x8*>(Hq + (size_t)i0_ * 128);\
    const f16x8* r1_ = reinterpret_cast<const f16x8*>(Hq + (size_t)i1_ * 128);\
    const f16x8* r2_ = reinterpret_cast<const f16x8*>(Hq + (size_t)i2_ * 128);\
    const f16x8* r3_ = reinterpret_cast<const f16x8*>(Hq + (size_t)i3_ * 128);\
    BUF[0] = r0_[0]; BUF[1] = r0_[1]; BUF[2] = r0_[2]; BUF[3] = r0_[3];       \
    BUF[4] = r1_[0]; BUF[5] = r1_[1]; BUF[6] = r1_[2]; BUF[7] = r1_[3];       \
    BUF[8] = r2_[0]; BUF[9] = r2_[1]; BUF[10] = r2_[2]; BUF[11] = r2_[3];     \
    BUF[12] = r3_[0]; BUF[13] = r3_[1]; BUF[14] = r3_[2]; BUF[15] = r3_[3];   \
  }

#define MATHG(BUF)                                                            \
  {                                                                           \
    acc_f16x8(acc[0], acc[1], BUF[0]); acc_f16x8(acc[2], acc[3], BUF[1]);     \
    acc_f16x8(acc[4], acc[5], BUF[2]); acc_f16x8(acc[6], acc[7], BUF[3]);     \
    acc_f16x8(acc[0], acc[1], BUF[4]); acc_f16x8(acc[2], acc[3], BUF[5]);     \
    acc_f16x8(acc[4], acc[5], BUF[6]); acc_f16x8(acc[6], acc[7], BUF[7]);     \
    acc_f16x8(acc[0], acc[1], BUF[8]); acc_f16x8(acc[2], acc[3], BUF[9]);     \
    acc_f16x8(acc[4], acc[5], BUF[10]); acc_f16x8(acc[6], acc[7], BUF[11]);   \
    acc_f16x8(acc[0], acc[1], BUF[12]); acc_f16x8(acc[2], acc[3], BUF[13]);   \
    acc_f16x8(acc[4], acc[5], BUF[14]); acc_f16x8(acc[6], acc[7], BUF[15]);   \
  }

// -------- fused GCN layer (d=128, fp16 H): agg = gather(H); v = relu(agg@W)+H
// Gather: wave q owns cols [32q,32q+32); lane l owns node n0+l; LDS-staged CSR
// slice; A/B ping-pong pipelined 4-edge groups + masked single-group tail.
// GEMM: MFMA 16x16x32_f16. mode 0: out = v. mode 1: G[gid] += v (pool fused).
__global__ __launch_bounds__(256, 2) void k_gcn_fused(
    const _Float16* __restrict__ H, const int* __restrict__ csr,
    const int* __restrict__ offs, const int* __restrict__ cnts,
    const _Float16* __restrict__ WT, _Float16* __restrict__ out,
    float* G, const int* __restrict__ gid, int N, int E, int mode) {
  __shared__ _Float16 sa_h[64 * 136];  // padded: row stride 272 B
  int* sidx = reinterpret_cast<int*>(sa_h);  // aliased during gather
  int n0 = blockIdx.x * 64;

  int e0 = offs[n0];
  int e1 = (n0 + 64 < N) ? offs[n0 + 64] : E;
  int nedge = e1 - e0;
  bool staged = (nedge <= 64 * 136 / 2);

  if (staged) {
    for (int i = threadIdx.x; i < nedge; i += 256) sidx[i] = csr[e0 + i];
  }
  __syncthreads();

  // ---- gather phase (fp32 acc in regs) ----
  int q = threadIdx.x >> 6;  // column quarter
  int l = threadIdx.x & 63;  // node lane
  {
    int n = n0 + l;
    float4 acc[8];
#pragma unroll
    for (int i = 0; i < 8; ++i) acc[i] = make_float4(0.f, 0.f, 0.f, 0.f);
    int cnt = (n < N) ? cnts[n] : 0;
    int sb = (n < N) ? (offs[n] - e0) : 0;
    const _Float16* Hq = H + q * 32;
    if (staged) {
      int ngf = cnt >> 2;   // full 4-edge groups
      int rem = cnt & 3;
      f16x8 Abuf[16], Bbuf[16];
      if (ngf > 0) {
        LOADG(Abuf, 0);
        int g = 0;
        for (; g + 1 < ngf; g += 2) {
          LOADG(Bbuf, g + 1);
          MATHG(Abuf);
          if (g + 2 < ngf) LOADG(Abuf, g + 2);
          MATHG(Bbuf);
        }
        if (g < ngf) MATHG(Abuf);
      }
      if (rem) {
        int b_ = sb + (ngf << 2);
        int lastv = sidx[sb + cnt - 1];
        int i0 = sidx[b_];
        int i1 = (rem > 1) ? sidx[b_ + 1] : lastv;
        int i2 = (rem > 2) ? sidx[b_ + 2] : lastv;
        float s1 = (rem > 1) ? 1.f : 0.f;
        float s2 = (rem > 2) ? 1.f : 0.f;
        const f16x8* r0 = reinterpret_cast<const f16x8*>(Hq + (size_t)i0 * 128);
        const f16x8* r1 = reinterpret_cast<const f16x8*>(Hq + (size_t)i1 * 128);
        const f16x8* r2 = reinterpret_cast<const f16x8*>(Hq + (size_t)i2 * 128);
        f16x8 t0 = r0[0], t1 = r0[1], t2 = r0[2], t3 = r0[3];
        f16x8 u0 = r1[0], u1 = r1[1], u2 = r1[2], u3 = r1[3];
        f16x8 v0 = r2[0], v1 = r2[1], v2 = r2[2], v3 = r2[3];
        acc_f16x8(acc[0], acc[1], t0); acc_f16x8(acc[2], acc[3], t1);
        acc_f16x8(acc[4], acc[5], t2); acc_f16x8(acc[6], acc[7], t3);
        acc_fma8(acc[0], acc[1], u0, s1); acc_fma8(acc[2], acc[3], u1, s1);
        acc_fma8(acc[4], acc[5], u2, s1); acc_fma8(acc[6], acc[7], u3, s1);
        acc_fma8(acc[0], acc[1], v0, s2); acc_fma8(acc[2], acc[3], v1, s2);
        acc_fma8(acc[4], acc[5], v2, s2); acc_fma8(acc[6], acc[7], v3, s2);
      }
    } else {
      int s = (n < N) ? offs[n] : 0;
      for (int e = 0; e < cnt; ++e) {
        int s0 = csr[s + e];
        const f16x8* r0 = reinterpret_cast<const f16x8*>(Hq + (size_t)s0 * 128);
        f16x8 a0 = r0[0], a1 = r0[1], a2 = r0[2], a3 = r0[3];
        acc_f16x8(acc[0], acc[1], a0); acc_f16x8(acc[2], acc[3], a1);
        acc_f16x8(acc[4], acc[5], a2); acc_f16x8(acc[6], acc[7], a3);
      }
    }
    __syncthreads();  // all sidx reads done; sa_h can be overwritten
    // store agg as fp16 (A-tile for MFMA)
    float* af = reinterpret_cast<float*>(acc);
#pragma unroll
    for (int j = 0; j < 4; ++j) {
      f16x8 st;
#pragma unroll
      for (int i = 0; i < 8; ++i) st[i] = (_Float16)af[j * 8 + i];
      *reinterpret_cast<f16x8*>(&sa_h[l * 136 + q * 32 + j * 8]) = st;
    }
  }
  __syncthreads();

  // ---- MFMA GEMM: C[64][128] = sa_h[64][128] @ W ; wave w -> cols [32w,32w+32)
  {
    int w = threadIdx.x >> 6;
    int lane = threadIdx.x & 63;
    int lr = lane & 15;
    int lg = lane >> 4;
    f32x4 C[4][2];
#pragma unroll
    for (int mt = 0; mt < 4; ++mt)
#pragma unroll
      for (int nt = 0; nt < 2; ++nt) C[mt][nt] = (f32x4){0.f, 0.f, 0.f, 0.f};
    const _Float16* WTb = WT + (size_t)(w * 32) * 128;
#pragma unroll
    for (int kk = 0; kk < 4; ++kk) {
      int k0 = kk * 32 + lg * 8;
      f16x8 a0 = *reinterpret_cast<const f16x8*>(&sa_h[(0 + lr) * 136 + k0]);
      f16x8 a1 = *reinterpret_cast<const f16x8*>(&sa_h[(16 + lr) * 136 + k0]);
      f16x8 a2 = *reinterpret_cast<const f16x8*>(&sa_h[(32 + lr) * 136 + k0]);
      f16x8 a3 = *reinterpret_cast<const f16x8*>(&sa_h[(48 + lr) * 136 + k0]);
      f16x8 b0 = *reinterpret_cast<const f16x8*>(&WTb[(size_t)lr * 128 + k0]);
      f16x8 b1 = *reinterpret_cast<const f16x8*>(&WTb[(size_t)(16 + lr) * 128 + k0]);
      C[0][0] = __builtin_amdgcn_mfma_f32_16x16x32_f16(a0, b0, C[0][0], 0, 0, 0);
      C[1][0] = __builtin_amdgcn_mfma_f32_16x16x32_f16(a1, b0, C[1][0], 0, 0, 0);
      C[2][0] = __builtin_amdgcn_mfma_f32_16x16x32_f16(a2, b0, C[2][0], 0, 0, 0);
      C[3][0] = __builtin_amdgcn_mfma_f32_16x16x32_f16(a3, b0, C[3][0], 0, 0, 0);
      C[0][1] = __builtin_amdgcn_mfma_f32_16x16x32_f16(a0, b1, C[0][1], 0, 0, 0);
      C[1][1] = __builtin_amdgcn_mfma_f32_16x16x32_f16(a1, b1, C[1][1], 0, 0, 0);
      C[2][1] = __builtin_amdgcn_mfma_f32_16x16x32_f16(a2, b1, C[2][1], 0, 0, 0);
      C[3][1] = __builtin_amdgcn_mfma_f32_16x16x32_f16(a3, b1, C[3][1], 0, 0, 0);
    }
    __syncthreads();  // all A reads complete before overwrite
    // write relu(C) back to sa_h (C/D layout: col=lane&15, row=(lane>>4)*4+r)
#pragma unroll
    for (int mt = 0; mt < 4; ++mt)
#pragma unroll
      for (int nt = 0; nt < 2; ++nt)
#pragma unroll
        for (int r = 0; r < 4; ++r) {
          int row = mt * 16 + lg * 4 + r;
          int col = w * 32 + nt * 16 + lr;
          sa_h[row * 136 + col] = (_Float16)fmaxf(C[mt][nt][r], 0.f);
        }
  }
  __syncthreads();

  // ---- epilogue: v = relu(C) + H (residual); store or pool ----
  int nl = threadIdx.x >> 4;
  int j0 = (threadIdx.x & 15) * 8;
  if (mode == 0) {
#pragma unroll
    for (int r = 0; r < 4; ++r) {
      int row = nl + 16 * r;
      int n = n0 + row;
      if (n < N) {
        size_t base = (size_t)n * 128 + j0;
        f16x8 vv = *reinterpret_cast<const f16x8*>(&sa_h[row * 136 + j0]);
        f16x8 hh = *reinterpret_cast<const f16x8*>(H + base);
        f16x8 o;
#pragma unroll
        for (int i = 0; i < 8; ++i) o[i] = (_Float16)((float)vv[i] + (float)hh[i]);
        *reinterpret_cast<f16x8*>(out + base) = o;
      }
    }
  } else {
#pragma unroll
    for (int r = 0; r < 4; ++r) {
      int row = nl + 16 * r;
      int n = n0 + row;
      if (n < N) {
        size_t base = (size_t)n * 128 + j0;
        f16x8 vv = *reinterpret_cast<const f16x8*>(&sa_h[row * 136 + j0]);
        f16x8 hh = *reinterpret_cast<const f16x8*>(H + base);
        f16x8 o;
#pragma unroll
        for (int i = 0; i < 8; ++i) o[i] = (_Float16)((float)vv[i] + (float)hh[i]);
        *reinterpret_cast<f16x8*>(&sa_h[row * 136 + j0]) = o;
      }
    }
    __syncthreads();
    int grp = threadIdx.x >> 7;  // 0..1 -> rows [0,32) / [32,64)
    int j = threadIdx.x & 127;
    int r0 = grp * 32;
    int nfirst = n0 + r0;
    if (nfirst < N) {
      float pacc = 0.f;
      int cur = gid[nfirst];
      for (int r = r0; r < r0 + 32; ++r) {
        int n = n0 + r;
        if (n >= N) break;
        int g2 = gid[n];
        if (g2 != cur) {
          atomicAdd(&G[(size_t)cur * 128 + j], pacc);
          pacc = 0.f;
          cur = g2;
        }
        pacc += (float)sa_h[r * 136 + j];
      }
      atomicAdd(&G[(size_t)cur * 128 + j], pacc);
    }
  }
}

// ---------------- pred = relu(g @ W_p1) @ W_p2 + b ----------------
__global__ __launch_bounds__(64) void k_head(const float* __restrict__ g,
                                             const float* __restrict__ W1,
                                             const float* __restrict__ W2,
                                             const float* __restrict__ b,
                                             float* __restrict__ out) {
  int gi = blockIdx.x;
  int j = threadIdx.x;
  __shared__ float sg[128];
  sg[j] = g[(size_t)gi * 128 + j];
  sg[j + 64] = g[(size_t)gi * 128 + 64 + j];
  __syncthreads();
  float acc = 0.f;
#pragma unroll
  for (int k = 0; k < 128; ++k) acc = fmaf(sg[k], W1[k * 64 + j], acc);
  acc = fmaxf(acc, 0.f) * W2[j];
#pragma unroll
  for (int off = 32; off > 0; off >>= 1) acc += __shfl_down(acc, off);
  if (j == 0) out[gi] = acc + b[0];
}

extern "C" void kernel_launch(void* const* d_in, const int* in_sizes, int n_in,
                              void* d_out, int out_size, void* d_ws, size_t ws_size,
                              hipStream_t stream) {
  const float* x    = (const float*)d_in[0];
  const float* Wemb = (const float*)d_in[1];
  const float* Wg0  = (const float*)d_in[2];
  const float* Wg1  = (const float*)d_in[3];
  const float* Wg2  = (const float*)d_in[4];
  const float* Wp1  = (const float*)d_in[5];
  const float* Wp2  = (const float*)d_in[6];
  const float* bp2  = (const float*)d_in[7];
  const int* esrc   = (const int*)d_in[8];
  const int* edst   = (const int*)d_in[9];
  const int* gids   = (const int*)d_in[10];
  int N = in_sizes[0] / 35;
  int E = in_sizes[8];
  float* out = (float*)d_out;

  // workspace layout (bytes)
  char* wp = (char*)d_ws;
  float* h0 = (float*)wp;            wp += (size_t)N * 8 * sizeof(float);
  _Float16* P = (_Float16*)wp;       wp += (size_t)N * 128 * sizeof(_Float16);
  _Float16* Q = (_Float16*)wp;       wp += (size_t)N * 128 * sizeof(_Float16);
  float* G  = (float*)wp;            wp += (size_t)NUM_GRAPHS * 128 * sizeof(float);
  int* counts   = (int*)wp;          wp += (size_t)N * sizeof(int);
  int* offs     = (int*)wp;          wp += (size_t)N * sizeof(int);
  int* cursor   = (int*)wp;          wp += (size_t)N * sizeof(int);
  int* partials = (int*)wp;          wp += 512 * sizeof(int);
  int* csr      = (int*)wp;          wp += (size_t)E * sizeof(int);
  _Float16* WT1 = (_Float16*)wp;     wp += (size_t)128 * 128 * sizeof(_Float16);
  _Float16* WT2 = (_Float16*)wp;

  int nbE = (E + 255) / 256;
  int nbN = (N + 255) / 256;

  // embed + weight prep (independent)
  k_embed<<<(N + 31) / 32, 256, 0, stream>>>(x, Wemb, h0, N);
  k_prepw<<<256, 128, 0, stream>>>(Wg1, Wg2, WT1, WT2);

  // CSR build
  hipMemsetAsync(counts, 0, (size_t)N * sizeof(int), stream);
  k_hist<<<nbE, 256, 0, stream>>>(edst, counts, E);
  k_scan1<<<nbN, 256, 0, stream>>>(counts, offs, partials, N);
  k_scan2<<<1, 512, 0, stream>>>(partials, nbN);
  k_scan3<<<nbN, 256, 0, stream>>>(offs, partials, cursor, N);
  k_fill<<<nbE, 256, 0, stream>>>(esrc, edst, cursor, csr, E);

  // zero pooled output (layer-2 epilogue atomics accumulate into it)
  hipMemsetAsync(G, 0, (size_t)NUM_GRAPHS * 128 * sizeof(float), stream);

  // layer 0: P = relu(gather(h0) @ W_g0)   (fp16 out)
  k_layer0<<<(N + 31) / 32, 256, 0, stream>>>(h0, csr, offs, counts, Wg0, P, N);

  // layer 1: Q = relu(gather(P) @ W_g1) + P
  k_gcn_fused<<<(N + 63) / 64, 256, 0, stream>>>(P, csr, offs, counts, WT1, Q,
                                                 nullptr, nullptr, N, E, 0);

  // layer 2 + pool: G[gid] += relu(gather(Q) @ W_g2) + Q
  k_gcn_fused<<<(N + 63) / 64, 256, 0, stream>>>(Q, csr, offs, counts, WT2, nullptr,
                                                 G, gids, N, E, 1);

  // head
  k_head<<<NUM_GRAPHS, 64, 0, stream>>>(G, Wp1, Wp2, bp2, out);
}

// Round 12
// 159.467 us; speedup vs baseline: 1.2074x; 1.2074x over previous
//
#include <hip/hip_runtime.h>

// GCNPredictor: 3-layer GCN (sum-aggregation) + sum-pool + MLP head.
// Round 12: k_gcn_fused reverted to R9 exactly (proven best, 48us/layer).
// Prologue consolidated: k_prep = embed(fp16 h0) + hist + W-transpose +
// G-zeroing in one launch (block-role ranges); scan2+scan3 fused (redundant
// LDS scan of partials per block); k_layer0 rewritten lane-per-node with
// fp16 h0 (1 load/edge). 13 -> 9 launches.

constexpr int NUM_GRAPHS = 2048;

typedef _Float16 f16x8 __attribute__((ext_vector_type(8)));
typedef float f32x4 __attribute__((ext_vector_type(4)));

// accumulate 8 halves into two float4 accumulators
__device__ __forceinline__ void acc_f16x8(float4& a0, float4& a1, const f16x8 h) {
  a0.x += (float)h[0]; a0.y += (float)h[1]; a0.z += (float)h[2]; a0.w += (float)h[3];
  a1.x += (float)h[4]; a1.y += (float)h[5]; a1.z += (float)h[6]; a1.w += (float)h[7];
}

// ---- k_prep: role-partitioned independent prologue work ----
// blocks [0, embedB): h0 = x @ W_emb (fp16 out)
// blocks [embedB, embedB+histB): counts histogram of edge_dst
// blocks [+0, +128): WT1/WT2 = W_g1^T / W_g2^T (fp16)
// blocks [+128, +192): zero G
__global__ __launch_bounds__(256) void k_prep(
    const float* __restrict__ x, const float* __restrict__ Wemb,
    _Float16* __restrict__ h0, const int* __restrict__ edst, int* counts,
    const float* __restrict__ W1, const float* __restrict__ W2,
    _Float16* __restrict__ WT1, _Float16* __restrict__ WT2,
    float* __restrict__ G, int N, int E, int embedB, int histB) {
  int b = blockIdx.x;
  if (b < embedB) {
    __shared__ float sx[32 * 35];
    __shared__ float sw[35 * 8];
    int n0 = b * 32;
    int cnt = min(32, N - n0);
    int nf = cnt * 35;
    for (int i = threadIdx.x; i < nf; i += 256) sx[i] = x[(size_t)n0 * 35 + i];
    for (int i = threadIdx.x; i < 35 * 8; i += 256) sw[i] = Wemb[i];
    __syncthreads();
    int nl = threadIdx.x >> 3;
    int c = threadIdx.x & 7;
    if (nl < cnt) {
      float acc = 0.f;
#pragma unroll
      for (int k = 0; k < 35; ++k)
        acc = fmaf(sx[nl * 35 + k], sw[k * 8 + c], acc);
      h0[(size_t)(n0 + nl) * 8 + c] = (_Float16)acc;
    }
    return;
  }
  b -= embedB;
  if (b < histB) {
    int e = b * 256 + threadIdx.x;
    if (e < E) atomicAdd(&counts[edst[e]], 1);
    return;
  }
  b -= histB;
  if (b < 128) {
    int k = threadIdx.x & 127;
    if (threadIdx.x < 128)
      WT1[(size_t)b * 128 + k] = (_Float16)W1[(size_t)k * 128 + b];
    else
      WT2[(size_t)b * 128 + k] = (_Float16)W2[(size_t)k * 128 + b];
    return;
  }
  b -= 128;
  if (b < 64) {
    float4* g4 = reinterpret_cast<float4*>(G);
#pragma unroll
    for (int r = 0; r < 4; ++r)
      g4[b * 1024 + r * 256 + threadIdx.x] = make_float4(0.f, 0.f, 0.f, 0.f);
  }
}

// ---------------- CSR scan: per-block inclusive scan + block sums ----------
__global__ __launch_bounds__(256) void k_scan1(const int* __restrict__ counts,
                                               int* __restrict__ offs,
                                               int* __restrict__ partials, int N) {
  __shared__ int s[256];
  int i = blockIdx.x * 256 + threadIdx.x;
  int v = (i < N) ? counts[i] : 0;
  s[threadIdx.x] = v;
  __syncthreads();
#pragma unroll
  for (int d = 1; d < 256; d <<= 1) {
    int t = (threadIdx.x >= d) ? s[threadIdx.x - d] : 0;
    __syncthreads();
    s[threadIdx.x] += t;
    __syncthreads();
  }
  if (i < N) offs[i] = s[threadIdx.x] - v;  // exclusive within block
  if (threadIdx.x == 255) partials[blockIdx.x] = s[255];
}

// ---- scan2+scan3 fused: every block redundantly scans partials in LDS ----
__global__ __launch_bounds__(512) void k_scan23(int* __restrict__ offs,
                                                const int* __restrict__ partials,
                                                int* __restrict__ cursor,
                                                int N, int nb) {
  __shared__ int s[512];
  __shared__ int base;
  int t = threadIdx.x;
  int v = (t < nb) ? partials[t] : 0;
  s[t] = v;
  __syncthreads();
#pragma unroll
  for (int d = 1; d < 512; d <<= 1) {
    int u = (t >= d) ? s[t - d] : 0;
    __syncthreads();
    s[t] += u;
    __syncthreads();
  }
  if (t == (int)blockIdx.x) base = s[t] - v;  // exclusive prefix of this block
  __syncthreads();
  if (t < 256) {
    int i = blockIdx.x * 256 + t;
    if (i < N) {
      int val = offs[i] + base;
      offs[i] = val;
      cursor[i] = val;
    }
  }
}

__global__ __launch_bounds__(256) void k_fill(const int* __restrict__ src,
                                              const int* __restrict__ dst,
                                              int* cursor, int* __restrict__ csr,
                                              int E) {
  int e = blockIdx.x * 256 + threadIdx.x;
  if (e < E) {
    int slot = atomicAdd(&cursor[dst[e]], 1);
    csr[slot] = src[e];
  }
}

// -------- layer 0: agg8 = gather(h0 fp16); out = relu(agg8 @ W_g0), fp16 out
// Lane-per-node over 256-node tile; 1x16B load per edge, 4-edge unroll,
// LDS-staged CSR slice; per-thread 8->128 GEMM from LDS weights.
__global__ __launch_bounds__(256) void k_layer0(const _Float16* __restrict__ h0,
                                                const int* __restrict__ csr,
                                                const int* __restrict__ offs,
                                                const int* __restrict__ cnts,
                                                const float* __restrict__ W,
                                                _Float16* __restrict__ out,
                                                int N, int E) {
  __shared__ float sw[8 * 128];
  __shared__ int sidx[3072];
  for (int i = threadIdx.x; i < 1024; i += 256) sw[i] = W[i];
  int n0 = blockIdx.x * 256;
  int e0 = offs[n0];
  int e1 = (n0 + 256 < N) ? offs[n0 + 256] : E;
  int nedge = e1 - e0;
  bool staged = (nedge <= 3072);
  if (staged) {
    for (int i = threadIdx.x; i < nedge; i += 256) sidx[i] = csr[e0 + i];
  }
  __syncthreads();

  int n = n0 + (int)threadIdx.x;
  float4 A0 = {0.f, 0.f, 0.f, 0.f}, A1 = A0, B0 = A0, B1 = A0;
  int cnt = (n < N) ? cnts[n] : 0;
  int sb = (n < N) ? (offs[n] - e0) : 0;
  if (staged) {
    int e = 0;
    for (; e + 4 <= cnt; e += 4) {
      int i0 = sidx[sb + e], i1 = sidx[sb + e + 1];
      int i2 = sidx[sb + e + 2], i3 = sidx[sb + e + 3];
      f16x8 v0 = *reinterpret_cast<const f16x8*>(h0 + (size_t)i0 * 8);
      f16x8 v1 = *reinterpret_cast<const f16x8*>(h0 + (size_t)i1 * 8);
      f16x8 v2 = *reinterpret_cast<const f16x8*>(h0 + (size_t)i2 * 8);
      f16x8 v3 = *reinterpret_cast<const f16x8*>(h0 + (size_t)i3 * 8);
      acc_f16x8(A0, A1, v0);
      acc_f16x8(B0, B1, v1);
      acc_f16x8(A0, A1, v2);
      acc_f16x8(B0, B1, v3);
    }
    for (; e < cnt; ++e) {
      int i0 = sidx[sb + e];
      f16x8 v0 = *reinterpret_cast<const f16x8*>(h0 + (size_t)i0 * 8);
      acc_f16x8(A0, A1, v0);
    }
  } else {
    int s = (n < N) ? offs[n] : 0;
    for (int e = 0; e < cnt; ++e) {
      int i0 = csr[s + e];
      f16x8 v0 = *reinterpret_cast<const f16x8*>(h0 + (size_t)i0 * 8);
      acc_f16x8(A0, A1, v0);
    }
  }
  if (n >= N) return;
  A0.x += B0.x; A0.y += B0.y; A0.z += B0.z; A0.w += B0.w;
  A1.x += B1.x; A1.y += B1.y; A1.z += B1.z; A1.w += B1.w;

  float a[8] = {A0.x, A0.y, A0.z, A0.w, A1.x, A1.y, A1.z, A1.w};
  size_t base = (size_t)n * 128;
#pragma unroll
  for (int c0 = 0; c0 < 128; c0 += 32) {
    float o[32];
#pragma unroll
    for (int j = 0; j < 32; ++j) o[j] = 0.f;
#pragma unroll
    for (int k = 0; k < 8; ++k) {
      float av = a[k];
      const float* swk = &sw[k * 128 + c0];
#pragma unroll
      for (int j = 0; j < 32; ++j) o[j] = fmaf(av, swk[j], o[j]);
    }
#pragma unroll
    for (int v = 0; v < 4; ++v) {
      f16x8 st;
#pragma unroll
      for (int i = 0; i < 8; ++i) st[i] = (_Float16)fmaxf(o[v * 8 + i], 0.f);
      *reinterpret_cast<f16x8*>(out + base + c0 + v * 8) = st;
    }
  }
}

// -------- fused GCN layer (d=128, fp16 H): agg = gather(H); v = relu(agg@W)+H
// (R9 exact.) Gather: wave q owns cols [32q,32q+32); lane l owns node n0+l;
// LDS-staged CSR slice; 4-edge unroll. GEMM: MFMA 16x16x32_f16, WT = W^T fp16.
// mode 0: out[n] = v (fp16). mode 1: G[gid[n]] += v (pool fused, fp32 G).
__global__ __launch_bounds__(256, 4) void k_gcn_fused(
    const _Float16* __restrict__ H, const int* __restrict__ csr,
    const int* __restrict__ offs, const int* __restrict__ cnts,
    const _Float16* __restrict__ WT, _Float16* __restrict__ out,
    float* G, const int* __restrict__ gid, int N, int E, int mode) {
  __shared__ _Float16 sa_h[64 * 136];  // padded: row stride 272 B
  int* sidx = reinterpret_cast<int*>(sa_h);  // aliased during gather
  int n0 = blockIdx.x * 64;

  int e0 = offs[n0];
  int e1 = (n0 + 64 < N) ? offs[n0 + 64] : E;
  int nedge = e1 - e0;
  bool staged = (nedge <= 64 * 136 / 2);

  if (staged) {
    for (int i = threadIdx.x; i < nedge; i += 256) sidx[i] = csr[e0 + i];
  }
  __syncthreads();

  // ---- gather phase (fp32 acc in regs) ----
  int q = threadIdx.x >> 6;  // column quarter
  int l = threadIdx.x & 63;  // node lane
  {
    int n = n0 + l;
    float4 acc[8];
#pragma unroll
    for (int i = 0; i < 8; ++i) acc[i] = make_float4(0.f, 0.f, 0.f, 0.f);
    int cnt = (n < N) ? cnts[n] : 0;
    int sb = (n < N) ? (offs[n] - e0) : 0;
    const _Float16* Hq = H + q * 32;
    if (staged) {
      int e = 0;
      for (; e + 4 <= cnt; e += 4) {
        int i0 = sidx[sb + e], i1 = sidx[sb + e + 1];
        int i2 = sidx[sb + e + 2], i3 = sidx[sb + e + 3];
        const f16x8* r0 = reinterpret_cast<const f16x8*>(Hq + (size_t)i0 * 128);
        const f16x8* r1 = reinterpret_cast<const f16x8*>(Hq + (size_t)i1 * 128);
        const f16x8* r2 = reinterpret_cast<const f16x8*>(Hq + (size_t)i2 * 128);
        const f16x8* r3 = reinterpret_cast<const f16x8*>(Hq + (size_t)i3 * 128);
        f16x8 a0 = r0[0], a1 = r0[1], a2 = r0[2], a3 = r0[3];
        f16x8 b0 = r1[0], b1 = r1[1], b2 = r1[2], b3 = r1[3];
        f16x8 c0 = r2[0], c1 = r2[1], c2 = r2[2], c3 = r2[3];
        f16x8 d0 = r3[0], d1 = r3[1], d2 = r3[2], d3 = r3[3];
        acc_f16x8(acc[0], acc[1], a0); acc_f16x8(acc[2], acc[3], a1);
        acc_f16x8(acc[4], acc[5], a2); acc_f16x8(acc[6], acc[7], a3);
        acc_f16x8(acc[0], acc[1], b0); acc_f16x8(acc[2], acc[3], b1);
        acc_f16x8(acc[4], acc[5], b2); acc_f16x8(acc[6], acc[7], b3);
        acc_f16x8(acc[0], acc[1], c0); acc_f16x8(acc[2], acc[3], c1);
        acc_f16x8(acc[4], acc[5], c2); acc_f16x8(acc[6], acc[7], c3);
        acc_f16x8(acc[0], acc[1], d0); acc_f16x8(acc[2], acc[3], d1);
        acc_f16x8(acc[4], acc[5], d2); acc_f16x8(acc[6], acc[7], d3);
      }
      for (; e < cnt; ++e) {
        int s0 = sidx[sb + e];
        const f16x8* r0 = reinterpret_cast<const f16x8*>(Hq + (size_t)s0 * 128);
        f16x8 a0 = r0[0], a1 = r0[1], a2 = r0[2], a3 = r0[3];
        acc_f16x8(acc[0], acc[1], a0); acc_f16x8(acc[2], acc[3], a1);
        acc_f16x8(acc[4], acc[5], a2); acc_f16x8(acc[6], acc[7], a3);
      }
    } else {
      int s = (n < N) ? offs[n] : 0;
      for (int e = 0; e < cnt; ++e) {
        int s0 = csr[s + e];
        const f16x8* r0 = reinterpret_cast<const f16x8*>(Hq + (size_t)s0 * 128);
        f16x8 a0 = r0[0], a1 = r0[1], a2 = r0[2], a3 = r0[3];
        acc_f16x8(acc[0], acc[1], a0); acc_f16x8(acc[2], acc[3], a1);
        acc_f16x8(acc[4], acc[5], a2); acc_f16x8(acc[6], acc[7], a3);
      }
    }
    __syncthreads();  // all sidx reads done; sa_h can be overwritten
    // store agg as fp16 (A-tile for MFMA)
    float* af = reinterpret_cast<float*>(acc);
#pragma unroll
    for (int j = 0; j < 4; ++j) {
      f16x8 st;
#pragma unroll
      for (int i = 0; i < 8; ++i) st[i] = (_Float16)af[j * 8 + i];
      *reinterpret_cast<f16x8*>(&sa_h[l * 136 + q * 32 + j * 8]) = st;
    }
  }
  __syncthreads();

  // ---- MFMA GEMM: C[64][128] = sa_h[64][128] @ W ; wave w -> cols [32w,32w+32)
  {
    int w = threadIdx.x >> 6;
    int lane = threadIdx.x & 63;
    int lr = lane & 15;
    int lg = lane >> 4;
    f32x4 C[4][2];
#pragma unroll
    for (int mt = 0; mt < 4; ++mt)
#pragma unroll
      for (int nt = 0; nt < 2; ++nt) C[mt][nt] = (f32x4){0.f, 0.f, 0.f, 0.f};
    const _Float16* WTb = WT + (size_t)(w * 32) * 128;
#pragma unroll
    for (int kk = 0; kk < 4; ++kk) {
      int k0 = kk * 32 + lg * 8;
      f16x8 a0 = *reinterpret_cast<const f16x8*>(&sa_h[(0 + lr) * 136 + k0]);
      f16x8 a1 = *reinterpret_cast<const f16x8*>(&sa_h[(16 + lr) * 136 + k0]);
      f16x8 a2 = *reinterpret_cast<const f16x8*>(&sa_h[(32 + lr) * 136 + k0]);
      f16x8 a3 = *reinterpret_cast<const f16x8*>(&sa_h[(48 + lr) * 136 + k0]);
      f16x8 b0 = *reinterpret_cast<const f16x8*>(&WTb[(size_t)lr * 128 + k0]);
      f16x8 b1 = *reinterpret_cast<const f16x8*>(&WTb[(size_t)(16 + lr) * 128 + k0]);
      C[0][0] = __builtin_amdgcn_mfma_f32_16x16x32_f16(a0, b0, C[0][0], 0, 0, 0);
      C[1][0] = __builtin_amdgcn_mfma_f32_16x16x32_f16(a1, b0, C[1][0], 0, 0, 0);
      C[2][0] = __builtin_amdgcn_mfma_f32_16x16x32_f16(a2, b0, C[2][0], 0, 0, 0);
      C[3][0] = __builtin_amdgcn_mfma_f32_16x16x32_f16(a3, b0, C[3][0], 0, 0, 0);
      C[0][1] = __builtin_amdgcn_mfma_f32_16x16x32_f16(a0, b1, C[0][1], 0, 0, 0);
      C[1][1] = __builtin_amdgcn_mfma_f32_16x16x32_f16(a1, b1, C[1][1], 0, 0, 0);
      C[2][1] = __builtin_amdgcn_mfma_f32_16x16x32_f16(a2, b1, C[2][1], 0, 0, 0);
      C[3][1] = __builtin_amdgcn_mfma_f32_16x16x32_f16(a3, b1, C[3][1], 0, 0, 0);
    }
    __syncthreads();  // all A reads complete before overwrite
    // write relu(C) back to sa_h (C/D layout: col=lane&15, row=(lane>>4)*4+r)
#pragma unroll
    for (int mt = 0; mt < 4; ++mt)
#pragma unroll
      for (int nt = 0; nt < 2; ++nt)
#pragma unroll
        for (int r = 0; r < 4; ++r) {
          int row = mt * 16 + lg * 4 + r;
          int col = w * 32 + nt * 16 + lr;
          sa_h[row * 136 + col] = (_Float16)fmaxf(C[mt][nt][r], 0.f);
        }
  }
  __syncthreads();

  // ---- epilogue: v = relu(C) + H (residual); store or pool ----
  int nl = threadIdx.x >> 4;
  int j0 = (threadIdx.x & 15) * 8;
  if (mode == 0) {
#pragma unroll
    for (int r = 0; r < 4; ++r) {
      int row = nl + 16 * r;
      int n = n0 + row;
      if (n < N) {
        size_t base = (size_t)n * 128 + j0;
        f16x8 vv = *reinterpret_cast<const f16x8*>(&sa_h[row * 136 + j0]);
        f16x8 hh = *reinterpret_cast<const f16x8*>(H + base);
        f16x8 o;
#pragma unroll
        for (int i = 0; i < 8; ++i) o[i] = (_Float16)((float)vv[i] + (float)hh[i]);
        *reinterpret_cast<f16x8*>(out + base) = o;
      }
    }
  } else {
#pragma unroll
    for (int r = 0; r < 4; ++r) {
      int row = nl + 16 * r;
      int n = n0 + row;
      if (n < N) {
        size_t base = (size_t)n * 128 + j0;
        f16x8 vv = *reinterpret_cast<const f16x8*>(&sa_h[row * 136 + j0]);
        f16x8 hh = *reinterpret_cast<const f16x8*>(H + base);
        f16x8 o;
#pragma unroll
        for (int i = 0; i < 8; ++i) o[i] = (_Float16)((float)vv[i] + (float)hh[i]);
        *reinterpret_cast<f16x8*>(&sa_h[row * 136 + j0]) = o;
      }
    }
    __syncthreads();
    int grp = threadIdx.x >> 7;  // 0..1 -> rows [0,32) / [32,64)
    int j = threadIdx.x & 127;
    int r0 = grp * 32;
    int nfirst = n0 + r0;
    if (nfirst < N) {
      float pacc = 0.f;
      int cur = gid[nfirst];
      for (int r = r0; r < r0 + 32; ++r) {
        int n = n0 + r;
        if (n >= N) break;
        int g2 = gid[n];
        if (g2 != cur) {
          atomicAdd(&G[(size_t)cur * 128 + j], pacc);
          pacc = 0.f;
          cur = g2;
        }
        pacc += (float)sa_h[r * 136 + j];
      }
      atomicAdd(&G[(size_t)cur * 128 + j], pacc);
    }
  }
}

// ---------------- pred = relu(g @ W_p1) @ W_p2 + b ----------------
__global__ __launch_bounds__(64) void k_head(const float* __restrict__ g,
                                             const float* __restrict__ W1,
                                             const float* __restrict__ W2,
                                             const float* __restrict__ b,
                                             float* __restrict__ out) {
  int gi = blockIdx.x;
  int j = threadIdx.x;
  __shared__ float sg[128];
  sg[j] = g[(size_t)gi * 128 + j];
  sg[j + 64] = g[(size_t)gi * 128 + 64 + j];
  __syncthreads();
  float acc = 0.f;
#pragma unroll
  for (int k = 0; k < 128; ++k) acc = fmaf(sg[k], W1[k * 64 + j], acc);
  acc = fmaxf(acc, 0.f) * W2[j];
#pragma unroll
  for (int off = 32; off > 0; off >>= 1) acc += __shfl_down(acc, off);
  if (j == 0) out[gi] = acc + b[0];
}

extern "C" void kernel_launch(void* const* d_in, const int* in_sizes, int n_in,
                              void* d_out, int out_size, void* d_ws, size_t ws_size,
                              hipStream_t stream) {
  const float* x    = (const float*)d_in[0];
  const float* Wemb = (const float*)d_in[1];
  const float* Wg0  = (const float*)d_in[2];
  const float* Wg1  = (const float*)d_in[3];
  const float* Wg2  = (const float*)d_in[4];
  const float* Wp1  = (const float*)d_in[5];
  const float* Wp2  = (const float*)d_in[6];
  const float* bp2  = (const float*)d_in[7];
  const int* esrc   = (const int*)d_in[8];
  const int* edst   = (const int*)d_in[9];
  const int* gids   = (const int*)d_in[10];
  int N = in_sizes[0] / 35;
  int E = in_sizes[8];
  float* out = (float*)d_out;

  // workspace layout (bytes)
  char* wp = (char*)d_ws;
  _Float16* h0 = (_Float16*)wp;      wp += (size_t)N * 8 * sizeof(_Float16);
  _Float16* P = (_Float16*)wp;       wp += (size_t)N * 128 * sizeof(_Float16);
  _Float16* Q = (_Float16*)wp;       wp += (size_t)N * 128 * sizeof(_Float16);
  float* G  = (float*)wp;            wp += (size_t)NUM_GRAPHS * 128 * sizeof(float);
  int* counts   = (int*)wp;          wp += (size_t)N * sizeof(int);
  int* offs     = (int*)wp;          wp += (size_t)N * sizeof(int);
  int* cursor   = (int*)wp;          wp += (size_t)N * sizeof(int);
  int* partials = (int*)wp;          wp += 512 * sizeof(int);
  int* csr      = (int*)wp;          wp += (size_t)E * sizeof(int);
  _Float16* WT1 = (_Float16*)wp;     wp += (size_t)128 * 128 * sizeof(_Float16);
  _Float16* WT2 = (_Float16*)wp;

  int nbE = (E + 255) / 256;
  int nbN = (N + 255) / 256;
  int embedB = (N + 31) / 32;

  // 1) zero histogram counts
  hipMemsetAsync(counts, 0, (size_t)N * sizeof(int), stream);

  // 2) consolidated prologue: embed + hist + W-transpose + zero-G
  k_prep<<<embedB + nbE + 128 + 64, 256, 0, stream>>>(
      x, Wemb, h0, edst, counts, Wg1, Wg2, WT1, WT2, G, N, E, embedB, nbE);

  // 3-5) CSR build
  k_scan1<<<nbN, 256, 0, stream>>>(counts, offs, partials, N);
  k_scan23<<<nbN, 512, 0, stream>>>(offs, partials, cursor, N, nbN);
  k_fill<<<nbE, 256, 0, stream>>>(esrc, edst, cursor, csr, E);

  // 6) layer 0: P = relu(gather(h0) @ W_g0)   (fp16)
  k_layer0<<<(N + 255) / 256, 256, 0, stream>>>(h0, csr, offs, counts, Wg0, P,
                                                N, E);

  // 7) layer 1: Q = relu(gather(P) @ W_g1) + P
  k_gcn_fused<<<(N + 63) / 64, 256, 0, stream>>>(P, csr, offs, counts, WT1, Q,
                                                 nullptr, nullptr, N, E, 0);

  // 8) layer 2 + pool: G[gid] += relu(gather(Q) @ W_g2) + Q
  k_gcn_fused<<<(N + 63) / 64, 256, 0, stream>>>(Q, csr, offs, counts, WT2, nullptr,
                                                 G, gids, N, E, 1);

  // 9) head
  k_head<<<NUM_GRAPHS, 64, 0, stream>>>(G, Wp1, Wp2, bp2, out);
}